// Round 9
// baseline (5013.982 us; speedup 1.0000x reference)
//
#include <hip/hip_runtime.h>
#include <cstdint>
#include <cstddef>
#include <cstring>

// Problem constants (B,T,H,E) = (64,256,1024,1024)
constexpr int B_ = 64;
constexpr int T_ = 256;
constexpr int H_ = 1024;
constexpr int E_ = 1024;
constexpr int G3 = 3 * H_; // 3072 stacked gate rows [r; z; n]

typedef __attribute__((ext_vector_type(8))) short short8; // 8 bf16 = 4 VGPR
typedef __attribute__((ext_vector_type(4))) float f32x4;  // MFMA accumulator

__device__ __forceinline__ f32x4 mfma16(short8 a, short8 b, f32x4 c) {
  return __builtin_amdgcn_mfma_f32_16x16x32_bf16(a, b, c, 0, 0, 0);
}

// Split fp32 into bf16 hi + bf16 lo (RNE both). All 4 cross-products in the
// MFMA give ~fp32-accurate GEMM (bf16 products are exact in fp32 accum).
__device__ __forceinline__ void bf16_split(float f, unsigned short& hi, unsigned short& lo) {
  unsigned u = __float_as_uint(f);
  unsigned r = u + 0x7fff + ((u >> 16) & 1);
  hi = (unsigned short)(r >> 16);
  float fhi = __uint_as_float((unsigned)hi << 16);
  float res = f - fhi;
  unsigned v = __float_as_uint(res);
  unsigned s = v + 0x7fff + ((v >> 16) & 1);
  lo = (unsigned short)(s >> 16);
}

// Agent-scope coherent 8B accesses: read/write the device coherent point, so
// cross-XCD h-frag handoff needs NO L2 invalidation (weights stay L2-hot).
__device__ __forceinline__ void frag_store8(unsigned short* p, unsigned long long v) {
  __hip_atomic_store((unsigned long long*)(void*)p, v, __ATOMIC_RELAXED, __HIP_MEMORY_SCOPE_AGENT);
}
__device__ __forceinline__ unsigned long long frag_load8(const unsigned short* p) {
  return __hip_atomic_load((const unsigned long long*)(const void*)p, __ATOMIC_RELAXED, __HIP_MEMORY_SCOPE_AGENT);
}

// ---------------------------------------------------------------------------
// Kernel 1: x_gates GEMM (SGEMM-NT, fp32) — unchanged (round-3/4 proven).
// Known DS-bound ~1.5:1 (4x ds_read_b128 vs 128cy VALU per kk/wave); next
// target after scan validates + absmax headroom confirmed: bf16 hi/lo MFMA.
// ---------------------------------------------------------------------------
__global__ __launch_bounds__(256, 2) void xgates_gemm(
    const float* __restrict__ A,    // x  [16384][1024]
    const float* __restrict__ Bw,   // w_ih [3072][1024]
    const float* __restrict__ bias, // b_ih [3072]
    float* __restrict__ C)          // [256][64][3072]
{
  constexpr int BM = 128, BN = 128, BK = 32, K = 1024;
  __shared__ float As[BK][BM + 4];
  __shared__ float Bs[BK][BN + 4];
  const int bm = blockIdx.x * BM;
  const int bn = blockIdx.y * BN;
  const int tid = threadIdx.x;
  const int tx = tid & 15;
  const int ty = tid >> 4;

  float acc[8][8];
#pragma unroll
  for (int i = 0; i < 8; i++)
#pragma unroll
    for (int j = 0; j < 8; j++) acc[i][j] = 0.f;

  float4 pa[4], pb[4];
  auto gload = [&](int k0) {
#pragma unroll
    for (int i = 0; i < 4; i++) {
      int idx = tid + i * 256;
      int r   = idx >> 3;
      int c4  = (idx & 7) * 4;
      pa[i] = *reinterpret_cast<const float4*>(&A[(size_t)(bm + r) * K + k0 + c4]);
      pb[i] = *reinterpret_cast<const float4*>(&Bw[(size_t)(bn + r) * K + k0 + c4]);
    }
  };

  gload(0);
  for (int k0 = 0; k0 < K; k0 += BK) {
    if (k0) __syncthreads();
#pragma unroll
    for (int i = 0; i < 4; i++) {
      int idx = tid + i * 256;
      int r   = idx >> 3;
      int c4  = (idx & 7) * 4;
      As[c4 + 0][r] = pa[i].x; As[c4 + 1][r] = pa[i].y;
      As[c4 + 2][r] = pa[i].z; As[c4 + 3][r] = pa[i].w;
      Bs[c4 + 0][r] = pb[i].x; Bs[c4 + 1][r] = pb[i].y;
      Bs[c4 + 2][r] = pb[i].z; Bs[c4 + 3][r] = pb[i].w;
    }
    __syncthreads();
    if (k0 + BK < K) gload(k0 + BK);
#pragma unroll 8
    for (int kk = 0; kk < BK; kk++) {
      float a[8], b[8];
      *reinterpret_cast<float4*>(&a[0]) = *reinterpret_cast<const float4*>(&As[kk][tx * 8]);
      *reinterpret_cast<float4*>(&a[4]) = *reinterpret_cast<const float4*>(&As[kk][tx * 8 + 4]);
      *reinterpret_cast<float4*>(&b[0]) = *reinterpret_cast<const float4*>(&Bs[kk][ty * 8]);
      *reinterpret_cast<float4*>(&b[4]) = *reinterpret_cast<const float4*>(&Bs[kk][ty * 8 + 4]);
#pragma unroll
      for (int i = 0; i < 8; i++)
#pragma unroll
        for (int j = 0; j < 8; j++)
          acc[i][j] = fmaf(a[i], b[j], acc[i][j]);
    }
  }

#pragma unroll
  for (int i = 0; i < 8; i++) {
    int m = bm + tx * 8 + i;
    int b = m >> 8;
    int t = m & 255;
    float* crow = &C[((size_t)t * 64 + b) * G3 + bn + ty * 8];
#pragma unroll
    for (int j4 = 0; j4 < 2; j4++) {
      float4 v;
      v.x = acc[i][j4 * 4 + 0] + bias[bn + ty * 8 + j4 * 4 + 0];
      v.y = acc[i][j4 * 4 + 1] + bias[bn + ty * 8 + j4 * 4 + 1];
      v.z = acc[i][j4 * 4 + 2] + bias[bn + ty * 8 + j4 * 4 + 2];
      v.w = acc[i][j4 * 4 + 3] + bias[bn + ty * 8 + j4 * 4 + 3];
      *reinterpret_cast<float4*>(&crow[j4 * 4]) = v;
    }
  }
}

// ---------------------------------------------------------------------------
// Kernel P: pack w_hh into MFMA A-frag bf16 hi/lo (unchanged, round-4 proven).
// Slot d = ((blk*3+g)*32+kf)*64 + lane: row m=lane&15 (u=blk*16+m, gate g),
// k = kf*32 + (lane>>4)*8 + j. Same bijection as the B-frag producer.
// ---------------------------------------------------------------------------
__global__ __launch_bounds__(256) void prep_wfrag(
    const float* __restrict__ w_hh,
    unsigned short* __restrict__ whi,
    unsigned short* __restrict__ wlo)
{
  int d = blockIdx.x * 256 + threadIdx.x;
  int l    = d & 63;
  int slot = d >> 6;
  int kf   = slot & 31;
  int bg   = slot >> 5;
  int g    = bg % 3;
  int blk  = bg / 3;
  int row  = g * 1024 + blk * 16 + (l & 15);
  int k0   = kf * 32 + (l >> 4) * 8;
  const float* src = w_hh + (size_t)row * 1024 + k0;
  short8 vh, vl;
#pragma unroll
  for (int j = 0; j < 8; j++) {
    unsigned short h, lo;
    bf16_split(src[j], h, lo);
    vh[j] = (short)h;
    vl[j] = (short)lo;
  }
  *reinterpret_cast<short8*>(whi + (size_t)d * 8) = vh;
  *reinterpret_cast<short8*>(wlo + (size_t)d * 8) = vl;
}

// ---------------------------------------------------------------------------
// Kernel 2: PERSISTENT full GRU scan — one launch, 256 steps, custom grid
// barrier. Grid 64 blocks x 256 thr (<= 256 CUs -> co-resident by
// construction). Per step identical math to round-4 gru_step_mfma (proven,
// absmax 9.8e-4): block owns 16 units x 3 gates; wave owns K-slice wid*256;
// LDS combine; wave wid finishes batch cols wid*16..+15.
//
// vs multi-launch:
//  - h_prev in REGISTERS across steps; fp32 mirror written only at t==255.
//  - h-frag handoff via agent-scope 8B atomics (coherent point) -> no L2
//    flush anywhere -> weight A-frags stay L2-resident for all 256 steps.
//  - grid barrier: release fetch_add + s_sleep spin + acquire fence.
//    Monotone target (t+1)*64 -> rocprof dispatch-replay cannot deadlock.
//  - B-frag atomic loads manually double-buffered across unrolled kf loop
//    (static indices only — rule #20).
// Safety audit (r6): reads of frag buffer X at step t complete (consumed by
// MFMA, vmcnt-waited) before this block's end-of-step syncthreads; the
// counted barrier then orders them before ANY block's step-t+1 writes to X.
// ---------------------------------------------------------------------------
__global__ __launch_bounds__(256) void gru_scan(
    const float* __restrict__ xg,    // [256][64][3072]
    float* __restrict__ h_final,     // [1024][64] final h mirror (fc1 input)
    const unsigned short* __restrict__ whi,
    const unsigned short* __restrict__ wlo,
    unsigned short* __restrict__ f0h, unsigned short* __restrict__ f0l, // even-step in
    unsigned short* __restrict__ f1h, unsigned short* __restrict__ f1l, // odd-step in
    const float* __restrict__ b_hh,
    unsigned* __restrict__ cnt)      // grid-barrier counter (memset 0)
{
  __shared__ f32x4 args[3][4][4][64]; // [g][nt][srcwave][lane] = 48 KB
  const int tid  = threadIdx.x;
  const int lane = tid & 63;
  const int wid  = __builtin_amdgcn_readfirstlane(tid >> 6); // 0..3
  const int blk  = blockIdx.x;                               // 0..63
  const int u0   = blk * 16;

  // C layout (verified m89): col = lane&15 (batch), row = (lane>>4)*4 + reg.
  const int bcol  = wid * 16 + (lane & 15);
  const int urow0 = (lane >> 4) * 4;

  // Per-thread epilogue constants (hoisted out of the scan loop).
  float bhr[4], bhz[4], bhn[4];
#pragma unroll
  for (int r = 0; r < 4; r++) {
    int u = u0 + urow0 + r;
    bhr[r] = b_hh[u];
    bhz[r] = b_hh[1024 + u];
    bhn[r] = b_hh[2048 + u];
  }
  // Frag-store geometry (same bijection as prep_wfrag; constant per thread).
  const int u_s  = u0 + urow0;          // first of 4 consecutive units
  const int kf_s = u_s >> 5;
  const int j0_s = u_s & 7;             // 0 or 4 (urow0 multiple of 4)
  const int lp_s = (((u_s & 31) >> 3) << 4) | (bcol & 15);
  const int nt_s = bcol >> 4;
  const size_t off_s = ((size_t)(kf_s * 4 + nt_s) * 64 + lp_s) * 8 + j0_s;

  float h_prev[4] = {0.f, 0.f, 0.f, 0.f}; // h0 = 0

  for (int t = 0; t < T_; t++) {
    const unsigned short* hhi_in = (t & 1) ? f1h : f0h;
    const unsigned short* hlo_in = (t & 1) ? f1l : f0l;
    unsigned short* hhi_out = (t & 1) ? f0h : f1h;
    unsigned short* hlo_out = (t & 1) ? f0l : f1l;
    const float* xg_t = xg + (size_t)t * B_ * G3;

    // xg operand prefetch — issued before the MFMA loop, used in the
    // epilogue. Lines are fully consumed within the block (16 u's/line
    // match the block's unit range), so no HBM over-fetch.
    float xr[4], xz[4], xn[4];
#pragma unroll
    for (int r = 0; r < 4; r++) {
      int u = u0 + urow0 + r;
      xr[r] = xg_t[(size_t)bcol * G3 + u];
      xz[r] = xg_t[(size_t)bcol * G3 + 1024 + u];
      xn[r] = xg_t[(size_t)bcol * G3 + 2048 + u];
    }

    f32x4 acc[3][4];
#pragma unroll
    for (int g = 0; g < 3; g++)
#pragma unroll
      for (int nt = 0; nt < 4; nt++) acc[g][nt] = (f32x4){0.f, 0.f, 0.f, 0.f};

    // B-frag coherent loads, register-double-buffered across unrolled kf loop.
    unsigned long long bq[2][16]; // [parity][nt*4 + {hi0,hi1,lo0,lo1}]
    {
      const int kf = wid * 8;
#pragma unroll
      for (int nt = 0; nt < 4; nt++) {
        const unsigned short* bh = hhi_in + ((size_t)(kf * 4 + nt) * 64 + lane) * 8;
        const unsigned short* bl = hlo_in + ((size_t)(kf * 4 + nt) * 64 + lane) * 8;
        bq[0][nt * 4 + 0] = frag_load8(bh);
        bq[0][nt * 4 + 1] = frag_load8(bh + 4);
        bq[0][nt * 4 + 2] = frag_load8(bl);
        bq[0][nt * 4 + 3] = frag_load8(bl + 4);
      }
    }
#pragma unroll
    for (int kk = 0; kk < 8; kk++) {
      const int kf = wid * 8 + kk;
      if (kk < 7) { // prefetch next kf into the other parity
        const int kf2 = kf + 1;
#pragma unroll
        for (int nt = 0; nt < 4; nt++) {
          const unsigned short* bh = hhi_in + ((size_t)(kf2 * 4 + nt) * 64 + lane) * 8;
          const unsigned short* bl = hlo_in + ((size_t)(kf2 * 4 + nt) * 64 + lane) * 8;
          bq[(kk + 1) & 1][nt * 4 + 0] = frag_load8(bh);
          bq[(kk + 1) & 1][nt * 4 + 1] = frag_load8(bh + 4);
          bq[(kk + 1) & 1][nt * 4 + 2] = frag_load8(bl);
          bq[(kk + 1) & 1][nt * 4 + 3] = frag_load8(bl + 4);
        }
      }
      short8 Ah[3], Al[3];
#pragma unroll
      for (int g = 0; g < 3; g++) {
        size_t off = ((size_t)((blk * 3 + g) * 32 + kf) * 64 + lane) * 8;
        Ah[g] = *reinterpret_cast<const short8*>(whi + off); // L2-resident
        Al[g] = *reinterpret_cast<const short8*>(wlo + off);
      }
#pragma unroll
      for (int nt = 0; nt < 4; nt++) {
        union { unsigned long long q[2]; short8 v; } Bh, Bl;
        Bh.q[0] = bq[kk & 1][nt * 4 + 0]; Bh.q[1] = bq[kk & 1][nt * 4 + 1];
        Bl.q[0] = bq[kk & 1][nt * 4 + 2]; Bl.q[1] = bq[kk & 1][nt * 4 + 3];
#pragma unroll
        for (int g = 0; g < 3; g++) {
          acc[g][nt] = mfma16(Ah[g], Bh.v, acc[g][nt]);
          acc[g][nt] = mfma16(Ah[g], Bl.v, acc[g][nt]);
          acc[g][nt] = mfma16(Al[g], Bh.v, acc[g][nt]);
          acc[g][nt] = mfma16(Al[g], Bl.v, acc[g][nt]);
        }
      }
    }

    // Cross-wave K combine via LDS.
#pragma unroll
    for (int g = 0; g < 3; g++)
#pragma unroll
      for (int nt = 0; nt < 4; nt++) args[g][nt][wid][lane] = acc[g][nt];
    __syncthreads();

    f32x4 cg[3];
#pragma unroll
    for (int g = 0; g < 3; g++) {
      f32x4 s = args[g][wid][0][lane];
      s += args[g][wid][1][lane];
      s += args[g][wid][2][lane];
      s += args[g][wid][3][lane];
      cg[g] = s;
    }

    // Gate math; h stays in registers; frag stores are coherent 8B atomics.
    unsigned short hi4[4], lo4[4];
#pragma unroll
    for (int r = 0; r < 4; r++) {
      float hr = cg[0][r] + bhr[r];
      float hz = cg[1][r] + bhz[r];
      float hn = cg[2][r] + bhn[r];
      float rr = 1.f / (1.f + expf(-(xr[r] + hr)));
      float zz = 1.f / (1.f + expf(-(xz[r] + hz)));
      float nn = tanhf(xn[r] + rr * hn);
      float h  = (1.f - zz) * nn + zz * h_prev[r];
      h_prev[r] = h;
      bf16_split(h, hi4[r], lo4[r]);
    }
    unsigned long long hv = (unsigned long long)hi4[0] | ((unsigned long long)hi4[1] << 16) |
                            ((unsigned long long)hi4[2] << 32) | ((unsigned long long)hi4[3] << 48);
    unsigned long long lv = (unsigned long long)lo4[0] | ((unsigned long long)lo4[1] << 16) |
                            ((unsigned long long)lo4[2] << 32) | ((unsigned long long)lo4[3] << 48);
    frag_store8(hhi_out + off_s, hv);
    frag_store8(hlo_out + off_s, lv);

    if (t == T_ - 1) { // final mirror for fc1 (visibility via dispatch boundary)
#pragma unroll
      for (int r = 0; r < 4; r++)
        h_final[(size_t)(u0 + urow0 + r) * 64 + bcol] = h_prev[r];
    }

    // ---- grid barrier (skip after last step) ----
    if (t < T_ - 1) {
      __syncthreads(); // drains all waves' frag stores (vmcnt 0) + args reuse
      if (tid == 0) {
        __hip_atomic_fetch_add(cnt, 1u, __ATOMIC_RELEASE, __HIP_MEMORY_SCOPE_AGENT);
        const unsigned target = (unsigned)(t + 1) * 64u;
        while (__hip_atomic_load(cnt, __ATOMIC_RELAXED, __HIP_MEMORY_SCOPE_AGENT) < target) {
          __builtin_amdgcn_s_sleep(1); // backoff: don't hammer the MALL line
        }
        __builtin_amdgcn_fence(__ATOMIC_ACQUIRE, "agent"); // close reorder window
      }
      __syncthreads(); // release block; subsequent frag reads are coherent atomics
    }
  }
}

// ---------------------------------------------------------------------------
// Kernel 3: small FC over transposed activations (runs once -> not hot).
// ---------------------------------------------------------------------------
template <int LEAKY, int STORE_T>
__global__ __launch_bounds__(256) void fc_kernel(
    const float* __restrict__ At,   // [K][64]
    const float* __restrict__ W,    // [N][K]
    const float* __restrict__ bias, // [N]
    float* __restrict__ out,        // [N][64] if STORE_T else [64][N]
    int N, int K)
{
  constexpr int KC = 128;
  __shared__ float a_s[KC][68];
  const int tid  = threadIdx.x;
  const int lane = tid & 63;
  const int wid  = __builtin_amdgcn_readfirstlane(tid >> 6);
  const int n0   = blockIdx.x * 16 + wid * 4;

  const float* __restrict__ w0 = W + (size_t)(n0 + 0) * K;
  const float* __restrict__ w1 = W + (size_t)(n0 + 1) * K;
  const float* __restrict__ w2 = W + (size_t)(n0 + 2) * K;
  const float* __restrict__ w3 = W + (size_t)(n0 + 3) * K;

  float acc0 = 0.f, acc1 = 0.f, acc2 = 0.f, acc3 = 0.f;
  for (int kc = 0; kc < K; kc += KC) {
#pragma unroll
    for (int i = 0; i < 8; i++) {
      int idx = tid + i * 256;
      int j   = idx >> 4;
      int c4  = (idx & 15) * 4;
      *reinterpret_cast<float4*>(&a_s[j][c4]) =
          *reinterpret_cast<const float4*>(&At[(size_t)(kc + j) * 64 + c4]);
    }
    __syncthreads();
#pragma unroll 16
    for (int j = 0; j < KC; j++) {
      float av = a_s[j][lane];
      acc0 = fmaf(av, w0[kc + j], acc0);
      acc1 = fmaf(av, w1[kc + j], acc1);
      acc2 = fmaf(av, w2[kc + j], acc2);
      acc3 = fmaf(av, w3[kc + j], acc3);
    }
    __syncthreads();
  }
  float r0 = acc0 + bias[n0 + 0];
  float r1 = acc1 + bias[n0 + 1];
  float r2 = acc2 + bias[n0 + 2];
  float r3 = acc3 + bias[n0 + 3];
  if (LEAKY) {
    r0 = (r0 >= 0.f) ? r0 : 0.2f * r0;
    r1 = (r1 >= 0.f) ? r1 : 0.2f * r1;
    r2 = (r2 >= 0.f) ? r2 : 0.2f * r2;
    r3 = (r3 >= 0.f) ? r3 : 0.2f * r3;
  }
  if (STORE_T) {
    out[(size_t)(n0 + 0) * 64 + lane] = r0;
    out[(size_t)(n0 + 1) * 64 + lane] = r1;
    out[(size_t)(n0 + 2) * 64 + lane] = r2;
    out[(size_t)(n0 + 3) * 64 + lane] = r3;
  } else {
    float4 v; v.x = r0; v.y = r1; v.z = r2; v.w = r3;
    *reinterpret_cast<float4*>(&out[(size_t)lane * N + n0]) = v;
  }
}

// ---------------------------------------------------------------------------
// Launch: prep_wfrag + xgates -> ONE persistent gru_scan -> fc1 -> fc2.
// Workspace (bytes): xg 201.3MB | hF 256KB | y1 256KB | whi/wlo 6.3MB x2 |
// 4 frag bufs 128KB ea | cnt 256B  ~= 214.6MB.
// ---------------------------------------------------------------------------
extern "C" void kernel_launch(void* const* d_in, const int* in_sizes, int n_in,
                              void* d_out, int out_size, void* d_ws, size_t ws_size,
                              hipStream_t stream) {
  (void)in_sizes; (void)n_in; (void)out_size; (void)ws_size;
  const float* x    = (const float*)d_in[0];
  const float* w_ih = (const float*)d_in[1];
  const float* w_hh = (const float*)d_in[2];
  const float* b_ih = (const float*)d_in[3];
  const float* b_hh = (const float*)d_in[4];
  const float* w1   = (const float*)d_in[5];
  const float* b1   = (const float*)d_in[6];
  const float* w2   = (const float*)d_in[7];
  const float* b2   = (const float*)d_in[8];
  float* out = (float*)d_out;

  char* p = (char*)d_ws;
  float* xg = (float*)p;            p += (size_t)T_ * B_ * G3 * 4;   // 201,326,592
  float* hF = (float*)p;            p += (size_t)H_ * B_ * 4;        // 262,144
  float* y1 = (float*)p;            p += (size_t)H_ * B_ * 4;        // 262,144
  unsigned short* whi = (unsigned short*)p; p += (size_t)G3 * H_ * 2; // 6,291,456
  unsigned short* wlo = (unsigned short*)p; p += (size_t)G3 * H_ * 2;
  unsigned short* f0h = (unsigned short*)p; p += 65536 * 2;           // 131,072 each
  unsigned short* f0l = (unsigned short*)p; p += 65536 * 2;
  unsigned short* f1h = (unsigned short*)p; p += 65536 * 2;
  unsigned short* f1l = (unsigned short*)p; p += 65536 * 2;
  unsigned* cnt = (unsigned*)p;     p += 256;

  // Zero-init: step-0 B-frags (h0 = 0) + barrier counter (ws is re-poisoned
  // 0xAA before every timed call, so these run every call; both are inside
  // the captured graph, so every replay resets them).
  hipMemsetAsync(f0h, 0, 2 * 65536 * 2, stream); // f0h + f0l contiguous
  hipMemsetAsync(cnt, 0, 256, stream);

  prep_wfrag<<<1536, 256, 0, stream>>>(w_hh, whi, wlo);
  xgates_gemm<<<dim3(128, 24), 256, 0, stream>>>(x, w_ih, b_ih, xg);

  gru_scan<<<64, 256, 0, stream>>>(xg, hF, whi, wlo, f0h, f0l, f1h, f1l, b_hh, cnt);

  fc_kernel<1, 1><<<64, 256, 0, stream>>>(hF, w1, b1, y1, H_, H_);
  fc_kernel<0, 0><<<64, 256, 0, stream>>>(y1, w2, b2, out, E_, H_);
}